// Round 1
// baseline (1131.387 us; speedup 1.0000x reference)
//
#include <hip/hip_runtime.h>
#include <stdint.h>
#include <math.h>

// ---------------- constants ----------------
#define SEQ    8
#define BATCH  128
#define NTOK   32
#define DIMK   1024
#define INNERD 1024
#define HEADS  16
#define DH     64
#define QNUM   64
#define FFH    4096
#define SCALE  0.125f

typedef __bf16 bf16;
typedef __bf16 bf16x8 __attribute__((ext_vector_type(8)));
typedef float  f32x4  __attribute__((ext_vector_type(4)));

__device__ __forceinline__ ushort f2b(float f) {
  union { float f; uint32_t u; } v; v.f = f;
  uint32_t u = v.u;
  return (ushort)((u + 0x7fffu + ((u >> 16) & 1u)) >> 16);
}
__device__ __forceinline__ float b2f(ushort s) {
  union { uint32_t u; float f; } v; v.u = ((uint32_t)s) << 16;
  return v.f;
}
__device__ __forceinline__ void g2l16(const ushort* g, ushort* l) {
  __builtin_amdgcn_global_load_lds(
      (const __attribute__((address_space(1))) void*)g,
      (__attribute__((address_space(3))) void*)l, 16, 0, 0);
}

// ---------------- conversion kernels ----------------
// x: (S,B,N,D) f32 -> xb: (S,N,B,D) bf16
__global__ __launch_bounds__(256) void conv_x_kernel(const float* __restrict__ x,
                                                     ushort* __restrict__ xb) {
  int idx = blockIdx.x * 256 + threadIdx.x;      // 8,388,608 chunks of 4
  int d4 = idx & 255;
  int n  = (idx >> 8) & 31;
  int b  = (idx >> 13) & 127;
  int s  = idx >> 20;
  float4 v = *(const float4*)(x + (size_t)(((s*128 + b)*32 + n) << 10) + (d4 << 2));
  ushort4 o;
  o.x = f2b(v.x); o.y = f2b(v.y); o.z = f2b(v.z); o.w = f2b(v.w);
  *(ushort4*)(xb + (size_t)(((s*32 + n)*128 + b) << 10) + (d4 << 2)) = o;
}

// q: (64,1024) f32 -> bf16 (same layout)
__global__ __launch_bounds__(256) void conv_q_kernel(const float* __restrict__ q,
                                                     ushort* __restrict__ qb) {
  int idx = blockIdx.x * 256 + threadIdx.x;      // 16384 chunks
  float4 v = *(const float4*)(q + (size_t)idx * 4);
  ushort4 o;
  o.x = f2b(v.x); o.y = f2b(v.y); o.z = f2b(v.z); o.w = f2b(v.w);
  *(ushort4*)(qb + (size_t)idx * 4) = o;
}

// Wt[r][k] = W[k][srccol(r)]  (bf16).  mode 1 = W1 GLU permutation.
__global__ __launch_bounds__(256) void transpose_w_kernel(const float* __restrict__ W,
                                                          ushort* __restrict__ Wt,
                                                          int K, int N, int mode) {
  __shared__ float tile[32][33];
  int rt = blockIdx.x, kt = blockIdx.y;
  int r0 = rt * 32;
  int src0;
  if (mode == 1) {
    int t = r0 >> 7, w = r0 & 127;
    src0 = (w < 64) ? (t*64 + w) : (4096 + t*64 + (w - 64));
  } else src0 = r0;
  int tx = threadIdx.x & 31, ty = threadIdx.x >> 5;
  for (int i = ty; i < 32; i += 8)
    tile[i][tx] = W[(size_t)(kt*32 + i) * N + src0 + tx];
  __syncthreads();
  for (int i = ty; i < 32; i += 8)
    Wt[(size_t)(r0 + i) * K + kt*32 + tx] = f2b(tile[tx][i]);
}

// ---------------- main GEMM (bf16 A [MxK], bf16 Bt [NxK]) ----------------
// EPI 0: store bf16 -> outb (stride Ncols)
// EPI 1: GLU epilogue -> hidden bf16 (stride 4096); bias = b1 (8192)
// EPI 2: float out = acc + bias[col] + resid  (stride Ncols)
template <int EPI>
__global__ __launch_bounds__(256) void gemm_bt(const ushort* __restrict__ A,
                                               const ushort* __restrict__ Bt,
                                               int K, int Ncols,
                                               float* __restrict__ outf,
                                               ushort* __restrict__ outb,
                                               const float* __restrict__ bias,
                                               const float* __restrict__ resid) {
  extern __shared__ char smem[];
  ushort* As = (ushort*)smem;          // 128x32
  ushort* Bs = As + 4096;              // 128x32
  const int nBn  = Ncols >> 7;
  const int bm = blockIdx.x / nBn, bn = blockIdx.x % nBn;
  const int t = threadIdx.x;
  const int wave = t >> 6, lane = t & 63;
  const int qq = lane >> 4, r = lane & 15;
  const int wm = ((wave >> 1) << 6), wn = ((wave & 1) << 6);

  const int rstg = t >> 2, cstg = (t & 3) << 3;
  const ushort* ag0 = A  + (size_t)(bm*128 + rstg) * K + cstg;
  const ushort* ag1 = ag0 + (size_t)64 * K;
  const ushort* bg0 = Bt + (size_t)(bn*128 + rstg) * K + cstg;
  const ushort* bg1 = bg0 + (size_t)64 * K;
  ushort* asw0 = As + wave * 512;
  ushort* asw1 = As + 2048 + wave * 512;
  ushort* bsw0 = Bs + wave * 512;
  ushort* bsw1 = Bs + 2048 + wave * 512;

  f32x4 acc[4][4] = {};

  for (int k0 = 0; k0 < K; k0 += 32) {
    g2l16(ag0 + k0, asw0);
    g2l16(ag1 + k0, asw1);
    g2l16(bg0 + k0, bsw0);
    g2l16(bg1 + k0, bsw1);
    __syncthreads();
    bf16x8 af[4], bfr[4];
#pragma unroll
    for (int i = 0; i < 4; i++) af[i]  = *(const bf16x8*)(As + (wm + i*16 + r)*32 + qq*8);
#pragma unroll
    for (int j = 0; j < 4; j++) bfr[j] = *(const bf16x8*)(Bs + (wn + j*16 + r)*32 + qq*8);
#pragma unroll
    for (int i = 0; i < 4; i++)
#pragma unroll
      for (int j = 0; j < 4; j++)
        acc[i][j] = __builtin_amdgcn_mfma_f32_16x16x32_bf16(af[i], bfr[j], acc[i][j], 0, 0, 0);
    __syncthreads();
  }

  if (EPI == 0) {
#pragma unroll
    for (int i = 0; i < 4; i++)
#pragma unroll
      for (int j = 0; j < 4; j++)
#pragma unroll
        for (int ii = 0; ii < 4; ii++) {
          int row = bm*128 + wm + i*16 + qq*4 + ii;
          int col = bn*128 + wn + j*16 + r;
          outb[(size_t)row * Ncols + col] = f2b(acc[i][j][ii]);
        }
  } else if (EPI == 1) {
    // u tile (128x128) -> LDS bf16 (stride 132), then GLU -> hidden (128x64)
    ushort* ut = (ushort*)smem;
#pragma unroll
    for (int i = 0; i < 4; i++)
#pragma unroll
      for (int j = 0; j < 4; j++)
#pragma unroll
        for (int ii = 0; ii < 4; ii++)
          ut[(wm + i*16 + qq*4 + ii)*132 + wn + j*16 + r] = f2b(acc[i][j][ii]);
    __syncthreads();
    for (int idx = t; idx < 8192; idx += 256) {
      int rr = idx >> 6, c = idx & 63;
      float a = b2f(ut[rr*132 + c])      + bias[bn*64 + c];
      float g = b2f(ut[rr*132 + 64 + c]) + bias[4096 + bn*64 + c];
      float ge = 0.5f * g * (1.0f + erff(g * 0.70710678118654752f));
      outb[(size_t)(bm*128 + rr) * 4096 + bn*64 + c] = f2b(a * ge);
    }
  } else {
#pragma unroll
    for (int i = 0; i < 4; i++)
#pragma unroll
      for (int j = 0; j < 4; j++)
#pragma unroll
        for (int ii = 0; ii < 4; ii++) {
          int row = bm*128 + wm + i*16 + qq*4 + ii;
          int col = bn*128 + wn + j*16 + r;
          size_t o = (size_t)row * Ncols + col;
          outf[o] = acc[i][j][ii] + bias[col] + resid[o];
        }
  }
}

// ---------------- attention ----------------
// one block per (s,n,h); kv: (S*N*B, 2048) bf16; out: (S*N*Q, 1024) f32
__global__ __launch_bounds__(256) void attn_kernel(const ushort* __restrict__ kv,
                                                   const ushort* __restrict__ qb,
                                                   const int* __restrict__ mask,
                                                   float* __restrict__ out) {
  __shared__ ushort Ks[128 * 72];   // K [b][d], stride 72 (144B = odd*16 -> conflict-free)
  __shared__ ushort Vt[64 * 136];   // V^T [d][b], stride 136
  __shared__ ushort Ps[64 * 136];   // attn [q][b], stride 136
  __shared__ float  Mrow[128];

  const int bid = blockIdx.x;
  const int h = bid & 15, n = (bid >> 4) & 31, s = bid >> 9;
  const size_t kvbase = (size_t)((s*32 + n) * 128) * 2048;
  const int t = threadIdx.x, wave = t >> 6, lane = t & 63;
  const int qq = lane >> 4, r = lane & 15;

  if (t < 128) Mrow[t] = (mask[s*128 + t] == 0) ? 1.0f : 0.0f;

  // stage K (head h): 1024 chunks of 8 elems
  for (int c = t; c < 1024; c += 256) {
    int b = c >> 3, d0 = (c & 7) * 8;
    uint4 v = *(const uint4*)(kv + kvbase + (size_t)b * 2048 + h*64 + d0);
    *(uint4*)(Ks + b*72 + d0) = v;
  }
  // stage V transposed: thread -> (b = t&127, dhalf = t>>7)
  {
    int b = t & 127, dh = t >> 7;
    for (int jj = 0; jj < 32; jj += 8) {
      uint4 v = *(const uint4*)(kv + kvbase + (size_t)b * 2048 + 1024 + h*64 + dh*32 + jj);
      const ushort* pv = (const ushort*)&v;
#pragma unroll
      for (int u8 = 0; u8 < 8; u8++)
        Vt[(dh*32 + jj + u8)*136 + b] = pv[u8];
    }
  }
  __syncthreads();

  // QK^T: wave handles q-rows [wave*16, +16)
  bf16x8 aq[2];
#pragma unroll
  for (int st = 0; st < 2; st++)
    aq[st] = *(const bf16x8*)(qb + (size_t)(wave*16 + r) * 1024 + h*64 + st*32 + qq*8);
  f32x4 sim[8];
#pragma unroll
  for (int jt = 0; jt < 8; jt++) {
    f32x4 c = {};
#pragma unroll
    for (int st = 0; st < 2; st++) {
      bf16x8 bk = *(const bf16x8*)(Ks + (jt*16 + r)*72 + st*32 + qq*8);
      c = __builtin_amdgcn_mfma_f32_16x16x32_bf16(aq[st], bk, c, 0, 0, 0);
    }
    sim[jt] = c;
  }

  // scale + mask (replace with -1e10, matching reference exactly)
#pragma unroll
  for (int jt = 0; jt < 8; jt++) {
    float mflag = Mrow[jt*16 + r];
#pragma unroll
    for (int ii = 0; ii < 4; ii++) {
      float v = sim[jt][ii] * SCALE;
      sim[jt][ii] = (mflag > 0.5f) ? -1e10f : v;
    }
  }
  // row max over the 16-lane group (cols live across r)
  float mx[4] = {-3.0e38f, -3.0e38f, -3.0e38f, -3.0e38f};
#pragma unroll
  for (int jt = 0; jt < 8; jt++)
#pragma unroll
    for (int ii = 0; ii < 4; ii++) mx[ii] = fmaxf(mx[ii], sim[jt][ii]);
#pragma unroll
  for (int m = 1; m < 16; m <<= 1)
#pragma unroll
    for (int ii = 0; ii < 4; ii++) mx[ii] = fmaxf(mx[ii], __shfl_xor(mx[ii], m));
  float sm[4] = {0.f, 0.f, 0.f, 0.f};
#pragma unroll
  for (int jt = 0; jt < 8; jt++)
#pragma unroll
    for (int ii = 0; ii < 4; ii++) {
      float e = expf(sim[jt][ii] - mx[ii]);
      sim[jt][ii] = e;
      sm[ii] += e;
    }
#pragma unroll
  for (int m = 1; m < 16; m <<= 1)
#pragma unroll
    for (int ii = 0; ii < 4; ii++) sm[ii] += __shfl_xor(sm[ii], m);
#pragma unroll
  for (int ii = 0; ii < 4; ii++) sm[ii] = 1.0f / sm[ii];
  // write P (bf16) in A-operand-friendly layout
#pragma unroll
  for (int jt = 0; jt < 8; jt++)
#pragma unroll
    for (int ii = 0; ii < 4; ii++)
      Ps[(wave*16 + qq*4 + ii)*136 + jt*16 + r] = f2b(sim[jt][ii] * sm[ii]);
  __syncthreads();

  // PV
  f32x4 o[4] = {};
#pragma unroll
  for (int kst = 0; kst < 4; kst++) {
    bf16x8 ap = *(const bf16x8*)(Ps + (wave*16 + r)*136 + kst*32 + qq*8);
#pragma unroll
    for (int jt2 = 0; jt2 < 4; jt2++) {
      bf16x8 bv = *(const bf16x8*)(Vt + (jt2*16 + r)*136 + kst*32 + qq*8);
      o[jt2] = __builtin_amdgcn_mfma_f32_16x16x32_bf16(ap, bv, o[jt2], 0, 0, 0);
    }
  }
  const size_t orow0 = (size_t)((s*32 + n) * 64);
#pragma unroll
  for (int jt2 = 0; jt2 < 4; jt2++)
#pragma unroll
    for (int ii = 0; ii < 4; ii++) {
      int qr = wave*16 + qq*4 + ii;
      int d  = jt2*16 + r;
      out[(orow0 + qr) * 1024 + h*64 + d] = o[jt2][ii];
    }
}

// ---------------- LayerNorm (in-place) + bf16 copy ----------------
__global__ __launch_bounds__(256) void ln_kernel(float* __restrict__ y,
                                                 ushort* __restrict__ yb,
                                                 const float* __restrict__ g,
                                                 const float* __restrict__ b) {
  __shared__ float r1[4], r2[4];
  const int row = blockIdx.x, t = threadIdx.x;
  const int wave = t >> 6, lane = t & 63;
  float* p = y + (size_t)row * 1024;
  float4 v = *(const float4*)(p + t*4);
  float s1 = v.x + v.y + v.z + v.w;
  float s2 = v.x*v.x + v.y*v.y + v.z*v.z + v.w*v.w;
#pragma unroll
  for (int m = 1; m < 64; m <<= 1) { s1 += __shfl_xor(s1, m); s2 += __shfl_xor(s2, m); }
  if (lane == 0) { r1[wave] = s1; r2[wave] = s2; }
  __syncthreads();
  s1 = r1[0] + r1[1] + r1[2] + r1[3];
  s2 = r2[0] + r2[1] + r2[2] + r2[3];
  float mu  = s1 * (1.0f/1024.0f);
  float var = s2 * (1.0f/1024.0f) - mu*mu;
  float inv = rsqrtf(var + 1e-5f);
  float4 gg = *(const float4*)(g + t*4);
  float4 bb = *(const float4*)(b + t*4);
  float4 o;
  o.x = (v.x - mu)*inv*gg.x + bb.x;
  o.y = (v.y - mu)*inv*gg.y + bb.y;
  o.z = (v.z - mu)*inv*gg.z + bb.z;
  o.w = (v.w - mu)*inv*gg.w + bb.w;
  *(float4*)(p + t*4) = o;
  ushort4 ob; ob.x = f2b(o.x); ob.y = f2b(o.y); ob.z = f2b(o.z); ob.w = f2b(o.w);
  *(ushort4*)(yb + (size_t)row * 1024 + t*4) = ob;
}

// ---------------- launcher ----------------
extern "C" void kernel_launch(void* const* d_in, const int* in_sizes, int n_in,
                              void* d_out, int out_size, void* d_ws, size_t ws_size,
                              hipStream_t stream) {
  const float* x    = (const float*)d_in[0];
  const int*   mask = (const int*)  d_in[1];
  const float* q    = (const float*)d_in[2];
  const float* Wkv  = (const float*)d_in[3];
  const float* lng  = (const float*)d_in[4];
  const float* lnb  = (const float*)d_in[5];
  const float* W1   = (const float*)d_in[6];
  const float* b1   = (const float*)d_in[7];
  const float* W2   = (const float*)d_in[8];
  const float* b2   = (const float*)d_in[9];
  float* out = (float*)d_out;
  char* ws = (char*)d_ws;

  // workspace layout (252.1 MiB total, with aliasing):
  ushort* xb   = (ushort*)(ws);               // 64 MiB  x_bf16 (S,N,B,D); dead after G1
  float*  yf   = (float*) (ws);               // alias: attn out / y (f32, 64 MiB)
  ushort* kvb  = (ushort*)(ws + 67108864);    // 128 MiB kv bf16; dead after attn
  ushort* hid  = (ushort*)(ws + 67108864);    // alias: hidden bf16 (128 MiB)
  ushort* yb   = (ushort*)(ws + 201326592);   // 32 MiB  y bf16
  ushort* wkvt = (ushort*)(ws + 234881024);   // 4 MiB
  ushort* w1t  = (ushort*)(ws + 239075328);   // 16 MiB (GLU-permuted rows)
  ushort* w2t  = (ushort*)(ws + 255852544);   // 8 MiB
  ushort* qb   = (ushort*)(ws + 264241152);   // 128 KiB

  conv_x_kernel<<<32768, 256, 0, stream>>>(x, xb);
  conv_q_kernel<<<64, 256, 0, stream>>>(q, qb);
  transpose_w_kernel<<<dim3(64, 32),  256, 0, stream>>>(Wkv, wkvt, 1024, 2048, 0);
  transpose_w_kernel<<<dim3(256, 32), 256, 0, stream>>>(W1,  w1t,  1024, 8192, 1);
  transpose_w_kernel<<<dim3(32, 128), 256, 0, stream>>>(W2,  w2t,  4096, 1024, 0);

  // kv = x @ W_kv  -> bf16 (32768 x 2048)
  gemm_bt<0><<<4096, 256, 16384, stream>>>(xb, wkvt, 1024, 2048, nullptr, kvb, nullptr, nullptr);
  // attention -> yf (16384 x 1024 f32)
  attn_kernel<<<4096, 256, 0, stream>>>(kvb, qb, mask, yf);
  // LayerNorm in place + bf16 copy
  ln_kernel<<<16384, 256, 0, stream>>>(yf, yb, lng, lnb);
  // FF1 + GLU -> hidden bf16 (16384 x 4096)
  gemm_bt<1><<<8192, 256, 33792, stream>>>(yb, w1t, 1024, 8192, nullptr, hid, b1, nullptr);
  // FF2 + bias + residual -> out f32
  gemm_bt<2><<<1024, 256, 16384, stream>>>(hid, w2t, 4096, 1024, out, nullptr, b2, yf);
}